// Round 7
// baseline (100.722 us; speedup 1.0000x reference)
//
#include <hip/hip_runtime.h>
#include <hip/hip_bf16.h>

// Problem: B=4, LQ=LK=1024, NHEADS=16, DK=64, D_MODEL=1024.
// out[b,i,d] = 0.125 * sum_{n,k} q[b,i,n,k] * T[b,n,k,d] + fc_b[d]
// T[b,n,k,d] = sum_j k[b,j,n,k] * fc_w[d, j*16+n]
// stage1 (fused): T2t[b][d][n*64+kk] = sum_j fc_w[d][j*16+n] * Kt[n][b*64+kk][j]
//   consumed DIRECTLY from fc_w via n-quad float4 loads (no Wt materialization).
// stage2: out[b] = 0.125 * Qb[b] @ T2t[b]^T + bias (4 batches, 1024^3)
// q->bf16 conversion rides gemm1f's epilogue.

typedef unsigned short u16;
typedef unsigned int u32;
typedef __bf16 bf16x8 __attribute__((ext_vector_type(8)));
typedef float f32x4 __attribute__((ext_vector_type(4)));

__device__ __forceinline__ u16 f2bf(float f) {
  union { float f; unsigned u; } in;
  in.f = f;
  unsigned u = in.u;
  u += 0x7fffu + ((u >> 16) & 1u);  // RNE
  return (u16)(u >> 16);
}

__device__ __forceinline__ u32 cvt_pk_bf16(float lo, float hi) {
  u32 r;
  asm("v_cvt_pk_bf16_f32 %0, %1, %2" : "=v"(r) : "v"(lo), "v"(hi));
  return r;
}

// ---------------- prep_k: Kt[n][b*64+kk][j] = k[b][j][n][kk] (R5-proven) ----------------
__global__ __launch_bounds__(256) void prep_k(const float* __restrict__ k,
                                              u16* __restrict__ Kt) {
  __shared__ u16 lds[64][65];
  const int tid = threadIdx.x;
  const int bid = blockIdx.x;
  int jt = bid & 15, n = (bid >> 4) & 15, b = bid >> 8;
  const int j0 = jt * 64;
  float4 r[4];
#pragma unroll
  for (int it = 0; it < 4; ++it) {
    int idx = it * 256 + tid;
    int jj = idx >> 4;
    int c4 = idx & 15;
    r[it] = *reinterpret_cast<const float4*>(
        &k[(((size_t)b * 1024 + j0 + jj) * 16 + n) * 64 + c4 * 4]);
  }
#pragma unroll
  for (int it = 0; it < 4; ++it) {
    int idx = it * 256 + tid;
    int jj = idx >> 4;
    int c4 = idx & 15;
    lds[c4 * 4 + 0][jj] = f2bf(r[it].x);
    lds[c4 * 4 + 1][jj] = f2bf(r[it].y);
    lds[c4 * 4 + 2][jj] = f2bf(r[it].z);
    lds[c4 * 4 + 3][jj] = f2bf(r[it].w);
  }
  __syncthreads();
  ushort4 o[4];
#pragma unroll
  for (int it = 0; it < 4; ++it) {
    int idx = it * 256 + tid;
    int kk = idx >> 4;
    int c4 = idx & 15;
    o[it].x = lds[kk][c4 * 4 + 0]; o[it].y = lds[kk][c4 * 4 + 1];
    o[it].z = lds[kk][c4 * 4 + 2]; o[it].w = lds[kk][c4 * 4 + 3];
  }
#pragma unroll
  for (int it = 0; it < 4; ++it) {
    int idx = it * 256 + tid;
    int kk = idx >> 4;
    int c4 = idx & 15;
    *reinterpret_cast<ushort4*>(
        &Kt[((size_t)n * 256 + b * 64 + kk) * 1024 + j0 + c4 * 4]) = o[it];
  }
}

// ---------------- gemm1f: fused de-interleave + GEMM ----------------
// grid dim3(64, 4): x = tm*4+tn (tm<16: 64-d tile; tn<4: 64-bk tile = batch b),
//                   y = nq (n-quad). wave w owns head n = nq*4+w, computes 64x64.
// A: reg-staged from fc_w (float4 = 4 heads for one (d,j)), cvt_pk -> swizzled LDS.
// B: Kt via global_load_lds with pre-swizzled source.
// LDS: A[2 buf][4 n'][64 d][64 j] bf16 + B[2 buf][4 n'][64 bk][64 j] = 128 KB.
__global__ __launch_bounds__(256, 1) void gemm1f(const float* __restrict__ fw,
                                                 const u16* __restrict__ Kt,
                                                 u16* __restrict__ T2t,
                                                 const float* __restrict__ qsrc,
                                                 u16* __restrict__ qdst) {
  __shared__ u16 LDS[65536];  // 128 KB
  u32* LDS32 = reinterpret_cast<u32*>(LDS);
  const int tid = threadIdx.x;
  const int w = tid >> 6;          // wave = head-within-quad
  const int lane = tid & 63;
  const int nq = blockIdx.y;
  const int tm = blockIdx.x >> 2;
  const int tn = blockIdx.x & 3;   // = batch b
  const int d0 = tm * 64;
  const int laneRow = lane & 15;
  const int hi = lane >> 4;

  f32x4 acc[4][4] = {};
  float4 ra[8], rb[8];

  // issue 16 float4 loads of fc_w for K-step t (j-pairs, n-quad fully used)
  auto loadA = [&](int t) {
    const int kt2 = t * 64;  // j base
#pragma unroll
    for (int i = 0; i < 8; ++i) {
      int c = i * 256 + tid;       // 0..2047
      int dd = c >> 5;             // 0..63
      int jp = c & 31;             // j-pair
      const float* base = fw + (size_t)(d0 + dd) * 16384 + (size_t)(kt2 + 2 * jp) * 16 + nq * 4;
      ra[i] = *reinterpret_cast<const float4*>(base);        // j = 2jp
      rb[i] = *reinterpret_cast<const float4*>(base + 16);   // j = 2jp+1
    }
  };

  // convert + swizzled LDS write (banks: lanes 0..31 distinct, 2-way across halves = free)
  auto writeA = [&](int buf) {
    const int wb = buf * 8192;  // u32 units
#pragma unroll
    for (int i = 0; i < 8; ++i) {
      int c = i * 256 + tid;
      int dd = c >> 5;
      int jp = c & 31;
      int jps = jp ^ ((dd & 7) << 2);
      int a = wb + dd * 32 + jps;
      LDS32[a + 0 * 2048] = cvt_pk_bf16(ra[i].x, rb[i].x);
      LDS32[a + 1 * 2048] = cvt_pk_bf16(ra[i].y, rb[i].y);
      LDS32[a + 2 * 2048] = cvt_pk_bf16(ra[i].z, rb[i].z);
      LDS32[a + 3 * 2048] = cvt_pk_bf16(ra[i].w, rb[i].w);
    }
  };

  // B: 4 head-tiles [64 bk][64 j] via async DMA, source col pre-swizzled
  auto stageB = [&](int t, int buf) {
    const int kt2 = t * 64;
#pragma unroll
    for (int i = 0; i < 8; ++i) {
      int p = i * 256 + tid;        // 16B chunk, 0..2047
      int np_ = p >> 9;             // head-within-quad
      int r = (p >> 3) & 63;        // bk row
      int cb2 = p & 7;              // 16B col block
      int scb = cb2 ^ (r & 7);      // pre-swizzled source block
      const u16* src = Kt + ((size_t)(nq * 4 + np_) * 256 + tn * 64 + r) * 1024 + kt2 + scb * 8;
      u16* dst = &LDS[32768 + buf * 16384 + p * 8];  // linear dest
      __builtin_amdgcn_global_load_lds(
          (const __attribute__((address_space(1))) void*)src,
          (__attribute__((address_space(3))) void*)dst, 16, 0, 0);
    }
  };

  auto compute = [&](int buf) {
    const int Ab = buf * 16384 + w * 4096;          // u16 units
    const int Bb = 32768 + buf * 16384 + w * 4096;
    bf16x8 af[2][4], bq[2][4];
#pragma unroll
    for (int kh = 0; kh < 2; ++kh) {
      int g = kh * 4 + hi;  // 16B col group 0..7
#pragma unroll
      for (int mi = 0; mi < 4; ++mi) {
        int dd = mi * 16 + laneRow;
        af[kh][mi] = *reinterpret_cast<const bf16x8*>(&LDS[Ab + dd * 64 + (g ^ (dd & 7)) * 8]);
      }
#pragma unroll
      for (int ni = 0; ni < 4; ++ni) {
        int rr = ni * 16 + laneRow;
        bq[kh][ni] = *reinterpret_cast<const bf16x8*>(&LDS[Bb + rr * 64 + (g ^ (rr & 7)) * 8]);
      }
    }
#pragma unroll
    for (int kh = 0; kh < 2; ++kh)
#pragma unroll
      for (int mi = 0; mi < 4; ++mi)
#pragma unroll
        for (int ni = 0; ni < 4; ++ni)
          acc[mi][ni] = __builtin_amdgcn_mfma_f32_16x16x32_bf16(
              af[kh][mi], bq[kh][ni], acc[mi][ni], 0, 0, 0);
  };

  // prologue
  loadA(0);
  stageB(0, 0);
  writeA(0);        // waits ra/rb via data dep
  __syncthreads();  // drains B-DMA (vmcnt) + A ds_writes (lgkm)

  for (int t = 0; t < 16; ++t) {
    const int cur = t & 1;
    if (t < 15) {
      stageB(t + 1, cur ^ 1);
      loadA(t + 1);
    }
    compute(cur);
    if (t < 15) {
      writeA(cur ^ 1);
      __syncthreads();
    }
  }

  // epilogue: wave w -> head n = nq*4+w; tile rows d0..d0+63, cols kk 0..63, b = tn
  const int n = nq * 4 + w;
#pragma unroll
  for (int mi = 0; mi < 4; ++mi) {
#pragma unroll
    for (int ni = 0; ni < 4; ++ni) {
      int colg = ni * 16 + laneRow;  // kk
#pragma unroll
      for (int qq = 0; qq < 4; ++qq) {
        int rowg = mi * 16 + hi * 4 + qq;
        T2t[(size_t)tn * 1048576 + (size_t)(d0 + rowg) * 1024 + n * 64 + colg] =
            f2bf(acc[mi][ni][qq]);
      }
    }
  }

  // q-tail: stream-convert this block's 64KB chunk of q -> Qb
  const int cb = nq * 64 + blockIdx.x;  // 0..255
  const float4* src = reinterpret_cast<const float4*>(qsrc) + (size_t)cb * 4096;
  ushort4* dst = reinterpret_cast<ushort4*>(qdst) + (size_t)cb * 4096;
#pragma unroll
  for (int rnd = 0; rnd < 4; ++rnd) {
    float4 r[4];
#pragma unroll
    for (int i = 0; i < 4; ++i) r[i] = src[rnd * 1024 + i * 256 + tid];
#pragma unroll
    for (int i = 0; i < 4; ++i) {
      ushort4 o;
      o.x = f2bf(r[i].x); o.y = f2bf(r[i].y);
      o.z = f2bf(r[i].z); o.w = f2bf(r[i].w);
      dst[rnd * 1024 + i * 256 + tid] = o;
    }
  }
}

// ---------------- gemm2 (unchanged, proven): out = 0.125 * Qb @ T2t^T + bias ----------------
template <int VM>
__device__ __forceinline__ void waitVm() {
  if constexpr (VM == 16) asm volatile("s_waitcnt vmcnt(16)" ::: "memory");
  else if constexpr (VM == 8) asm volatile("s_waitcnt vmcnt(8)" ::: "memory");
  else asm volatile("s_waitcnt vmcnt(0)" ::: "memory");
}

__global__ __launch_bounds__(256, 1) void gemm2(const u16* __restrict__ Abase,
                                                const u16* __restrict__ Bbase,
                                                float* __restrict__ CoutF,
                                                const float* __restrict__ bias) {
  __shared__ u16 AB[4][2][128 * 64];  // 128 KB
  const int tid = threadIdx.x;
  const int wid = tid >> 6;
  const int lane = tid & 63;
  const int batch = blockIdx.y;
  const int tm = blockIdx.x >> 3;
  const int tn = blockIdx.x & 7;

  const u16* A = Abase + (size_t)batch * 1048576;
  const u16* B = Bbase + (size_t)batch * 1048576;
  const int row0A = tm * 128, row0B = tn * 128;

  const int wr = wid >> 1;
  const int wc = wid & 1;
  const int laneRow = lane & 15;
  const int hi8 = (lane >> 4) * 8;
  const int swz = (lane & 7) * 8;

  f32x4 acc[4][4] = {};

  auto stage = [&](int tIdx) {
    const int kt = tIdx * 64;
    u16* lA = &AB[tIdx & 3][0][0];
    u16* lB = &AB[tIdx & 3][1][0];
#pragma unroll
    for (int i = 0; i < 4; ++i) {
      int p = i * 256 + tid;
      int r = p >> 3;
      int sc = ((p & 7) ^ (r & 7)) * 8;
      const u16* gA = A + (size_t)(row0A + r) * 1024 + kt + sc;
      const u16* gB = B + (size_t)(row0B + r) * 1024 + kt + sc;
      __builtin_amdgcn_global_load_lds(
          (const __attribute__((address_space(1))) void*)gA,
          (__attribute__((address_space(3))) void*)(lA + i * 2048 + wid * 512), 16, 0, 0);
      __builtin_amdgcn_global_load_lds(
          (const __attribute__((address_space(1))) void*)gB,
          (__attribute__((address_space(3))) void*)(lB + i * 2048 + wid * 512), 16, 0, 0);
    }
  };

  auto compute = [&](int tIdx) {
    const u16* At = &AB[tIdx & 3][0][0];
    const u16* Bt = &AB[tIdx & 3][1][0];
    bf16x8 af[2][4], bq[2][4];
#pragma unroll
    for (int kh = 0; kh < 2; ++kh) {
      int cs = (kh * 32 + hi8) ^ swz;
#pragma unroll
      for (int mi = 0; mi < 4; ++mi)
        af[kh][mi] = *reinterpret_cast<const bf16x8*>(
            &At[(wr * 64 + mi * 16 + laneRow) * 64 + cs]);
#pragma unroll
      for (int ni = 0; ni < 4; ++ni)
        bq[kh][ni] = *reinterpret_cast<const bf16x8*>(
            &Bt[(wc * 64 + ni * 16 + laneRow) * 64 + cs]);
    }
#pragma unroll
    for (int kh = 0; kh < 2; ++kh)
#pragma unroll
      for (int mi = 0; mi < 4; ++mi)
#pragma unroll
        for (int ni = 0; ni < 4; ++ni)
          acc[mi][ni] = __builtin_amdgcn_mfma_f32_16x16x32_bf16(
              af[kh][mi], bq[kh][ni], acc[mi][ni], 0, 0, 0);
  };

  stage(0); stage(1); stage(2);
  for (int t = 0; t < 13; ++t) {
    waitVm<16>();
    __builtin_amdgcn_s_barrier();
    stage(t + 3);
    compute(t);
  }
  waitVm<16>(); __builtin_amdgcn_s_barrier(); compute(13);
  waitVm<8>();  __builtin_amdgcn_s_barrier(); compute(14);
  waitVm<0>();  __builtin_amdgcn_s_barrier(); compute(15);

#pragma unroll
  for (int mi = 0; mi < 4; ++mi) {
#pragma unroll
    for (int ni = 0; ni < 4; ++ni) {
      int colg = tn * 128 + wc * 64 + ni * 16 + laneRow;
#pragma unroll
      for (int qq = 0; qq < 4; ++qq) {
        int rowg = tm * 128 + wr * 64 + mi * 16 + (lane >> 4) * 4 + qq;
        CoutF[(size_t)batch * 1048576 + (size_t)rowg * 1024 + colg] =
            acc[mi][ni][qq] * 0.125f + bias[colg];
      }
    }
  }
}

extern "C" void kernel_launch(void* const* d_in, const int* in_sizes, int n_in,
                              void* d_out, int out_size, void* d_ws, size_t ws_size,
                              hipStream_t stream) {
  const float* q    = (const float*)d_in[0];
  const float* k    = (const float*)d_in[1];
  // d_in[2] = v — unused by the reference output
  const float* fc_w = (const float*)d_in[3];
  const float* fc_b = (const float*)d_in[4];
  float* out = (float*)d_out;

  char* ws = (char*)d_ws;
  if (ws_size < 58720256) return;
  u16* Qb  = (u16*)(ws);             // [4][1024][1024]  8.4 MB
  u16* Kt  = (u16*)(ws + 8388608);   // [16][256][1024]  8.4 MB
  u16* T2t = (u16*)(ws + 50331648);  // [4][1024][1024]  8.4 MB

  prep_k<<<1024, 256, 0, stream>>>(k, Kt);
  gemm1f<<<dim3(64, 4), 256, 0, stream>>>(fc_w, Kt, T2t, q, Qb);
  gemm2<<<dim3(64, 4), 256, 0, stream>>>(Qb, T2t, out, fc_b);
}

// Round 9
// 96.204 us; speedup vs baseline: 1.0470x; 1.0470x over previous
//
#include <hip/hip_runtime.h>
#include <hip/hip_bf16.h>

// Problem: B=4, LQ=LK=1024, NHEADS=16, DK=64, D_MODEL=1024.
// out[b,i,d] = 0.125 * sum_{n,k} q[b,i,n,k] * T[b,n,k,d] + fc_b[d]
// T[b,n,k,d] = sum_j k[b,j,n,k] * fc_w[d, j*16+n]
// stage1 (gemm1f): T2t[b][d][n*64+kk] = sum_j fc_w[d][j*16+n] * Kt[n][b*64+kk][j]
//   Each block owns ALL 16 heads for a 16-d tile x one batch -> every byte of
//   the contiguous fc_w lines is consumed. fc_w never materialized as bf16.
// stage2 (gemm2): out[b] = 0.125 * Qb[b] @ T2t[b]^T + bias.
// q->bf16 conversion rides gemm1f's epilogue.

typedef unsigned short u16;
typedef unsigned int u32;
typedef __bf16 bf16x8 __attribute__((ext_vector_type(8)));
typedef float f32x4 __attribute__((ext_vector_type(4)));

#define AS1 __attribute__((address_space(1)))
#define AS3 __attribute__((address_space(3)))

__device__ __forceinline__ u16 f2bf(float f) {
  union { float f; unsigned u; } in;
  in.f = f;
  unsigned u = in.u;
  u += 0x7fffu + ((u >> 16) & 1u);  // RNE
  return (u16)(u >> 16);
}

__device__ __forceinline__ u32 cvt_pk_bf16(float lo, float hi) {
  u32 r;
  asm("v_cvt_pk_bf16_f32 %0, %1, %2" : "=v"(r) : "v"(lo), "v"(hi));
  return r;
}

// ---------------- prep_k: Kt[n][b*64+kk][j] = k[b][j][n][kk] (proven) ----------------
__global__ __launch_bounds__(256) void prep_k(const float* __restrict__ k,
                                              u16* __restrict__ Kt) {
  __shared__ u16 lds[64][65];
  const int tid = threadIdx.x;
  const int bid = blockIdx.x;
  int jt = bid & 15, n = (bid >> 4) & 15, b = bid >> 8;
  const int j0 = jt * 64;
  float4 r[4];
#pragma unroll
  for (int it = 0; it < 4; ++it) {
    int idx = it * 256 + tid;
    int jj = idx >> 4;
    int c4 = idx & 15;
    r[it] = *reinterpret_cast<const float4*>(
        &k[(((size_t)b * 1024 + j0 + jj) * 16 + n) * 64 + c4 * 4]);
  }
#pragma unroll
  for (int it = 0; it < 4; ++it) {
    int idx = it * 256 + tid;
    int jj = idx >> 4;
    int c4 = idx & 15;
    lds[c4 * 4 + 0][jj] = f2bf(r[it].x);
    lds[c4 * 4 + 1][jj] = f2bf(r[it].y);
    lds[c4 * 4 + 2][jj] = f2bf(r[it].z);
    lds[c4 * 4 + 3][jj] = f2bf(r[it].w);
  }
  __syncthreads();
  ushort4 o[4];
#pragma unroll
  for (int it = 0; it < 4; ++it) {
    int idx = it * 256 + tid;
    int kk = idx >> 4;
    int c4 = idx & 15;
    o[it].x = lds[kk][c4 * 4 + 0]; o[it].y = lds[kk][c4 * 4 + 1];
    o[it].z = lds[kk][c4 * 4 + 2]; o[it].w = lds[kk][c4 * 4 + 3];
  }
#pragma unroll
  for (int it = 0; it < 4; ++it) {
    int idx = it * 256 + tid;
    int kk = idx >> 4;
    int c4 = idx & 15;
    *reinterpret_cast<ushort4*>(
        &Kt[((size_t)n * 256 + b * 64 + kk) * 1024 + j0 + c4 * 4]) = o[it];
  }
}

// ---------------- gemm1f: all-heads fused de-interleave GEMM ----------------
// 256 blocks: o -> wg=(o&7)*32+(o>>3) (XCD-bijective; 4 batch-siblings of a
// d-slab share one XCD's L2); tm=wg>>2 (16-d tile), b=wg&3.
// Per block: C[16 d][1024 nk], 32 K-steps of BK=32 j.
// A: fc_w reg-staged (coalesced float4 pairs) -> cvt_pk -> LDS dbuf
//    layout u32 addr = n*324 + dd*20 + jp  (16B-aligned fragments; write 2-way).
// B: Kt via global_load_lds, single 64KB buffer [1024 rows][32 j], chunk-swizzle
//    c ^= (row&3)^((row>>2)&3) on both source and read (rule #21).
__global__ __launch_bounds__(256, 1) void gemm1f(const float* __restrict__ fw,
                                                 const u16* __restrict__ Kt,
                                                 u16* __restrict__ T2t,
                                                 const float* __restrict__ qsrc,
                                                 u16* __restrict__ qdst) {
  __shared__ __align__(16) u32 Albuf[2][16 * 324];  // 2 x 20.7 KB
  __shared__ __align__(16) u16 Bbuf[1024 * 32];     // 64 KB
  const int tid = threadIdx.x;
  const int w = tid >> 6, lane = tid & 63;
  const int o = blockIdx.x;
  const int wg = (o & 7) * 32 + (o >> 3);
  const int tm = wg >> 2, b = wg & 3;
  const int d0 = tm * 16;
  const int lr = lane & 15, lg = lane >> 4;

  f32x4 acc[4][4] = {};  // [head-within-wave hh][kk-frag ni]
  float4 rA[8];

  // A pair decode: p = i*256+tid -> nq=p&3, jp=(p>>2)&15 (j-pair), dd=p>>6
  auto issueA = [&](int t) {
    const int kt = t * 32;
#pragma unroll
    for (int i = 0; i < 4; ++i) {
      int p = i * 256 + tid;
      int nq = p & 3, jp = (p >> 2) & 15, dd = p >> 6;
      const float* base = fw + (size_t)(d0 + dd) * 16384 + (size_t)(kt + 2 * jp) * 16 + nq * 4;
      rA[2 * i]     = *reinterpret_cast<const float4*>(base);       // j = kt+2jp
      rA[2 * i + 1] = *reinterpret_cast<const float4*>(base + 16);  // j = kt+2jp+1
    }
  };
  auto writeA = [&](int buf) {
    u32* AB = &Albuf[buf][0];
#pragma unroll
    for (int i = 0; i < 4; ++i) {
      int p = i * 256 + tid;
      int nq = p & 3, jp = (p >> 2) & 15, dd = p >> 6;
      int base = dd * 20 + jp;
#pragma unroll
      for (int e = 0; e < 4; ++e)
        AB[(nq * 4 + e) * 324 + base] =
            cvt_pk_bf16((&rA[2 * i].x)[e], (&rA[2 * i + 1].x)[e]);
    }
  };
  auto stageB = [&](int t) {
    const int kt = t * 32;
#pragma unroll
    for (int i = 0; i < 16; ++i) {
      int p = i * 256 + tid;          // 0..4095 16B chunks
      int row = p >> 2, c = p & 3;    // row = n*64+kk, 4 chunks of 8 j
      int n = row >> 6, kk = row & 63;
      int sc = c ^ (row & 3) ^ ((row >> 2) & 3);
      const u16* src = Kt + ((size_t)n * 256 + b * 64 + kk) * 1024 + kt + sc * 8;
      __builtin_amdgcn_global_load_lds((const AS1 void*)src,
                                       (AS3 void*)(&Bbuf[p * 8]), 16, 0, 0);
    }
  };
  auto compute = [&](int buf) {
    const u16* AB16 = reinterpret_cast<const u16*>(&Albuf[buf][0]);
#pragma unroll
    for (int hh = 0; hh < 4; ++hh) {
      const int n = w * 4 + hh;
      bf16x8 af = *reinterpret_cast<const bf16x8*>(&AB16[n * 648 + lr * 40 + lg * 8]);
#pragma unroll
      for (int ni = 0; ni < 4; ++ni) {
        int row = n * 64 + ni * 16 + lr;               // output col = B row
        int cc = lg ^ (row & 3) ^ ((row >> 2) & 3);    // read-side swizzle
        bf16x8 bq = *reinterpret_cast<const bf16x8*>(&Bbuf[row * 32 + cc * 8]);
        acc[hh][ni] = __builtin_amdgcn_mfma_f32_16x16x32_bf16(af, bq, acc[hh][ni], 0, 0, 0);
      }
    }
  };

  // prologue
  issueA(0);
  asm volatile("s_waitcnt vmcnt(0)" ::: "memory");
  writeA(0);
  issueA(1);  // 8 outstanding

  for (int t = 0; t < 32; ++t) {
    stageB(t);  // +16
    if (t < 31) {
      asm volatile("s_waitcnt vmcnt(16)" ::: "memory");  // A(t+1) regs ready
      writeA((t + 1) & 1);
      if (t < 30) issueA(t + 2);  // +8
    }
    if (t < 30) asm volatile("s_waitcnt vmcnt(8)" ::: "memory");  // B(t) landed
    else        asm volatile("s_waitcnt vmcnt(0)" ::: "memory");
    asm volatile("s_waitcnt lgkmcnt(0)" ::: "memory");
    __builtin_amdgcn_s_barrier();
    compute(t & 1);
    __builtin_amdgcn_s_barrier();
  }

  // epilogue: C frag col=lane&15, row=(lane>>4)*4+q -> T2t[b][d0+row][n*64+col]
#pragma unroll
  for (int hh = 0; hh < 4; ++hh) {
    const int n = w * 4 + hh;
#pragma unroll
    for (int ni = 0; ni < 4; ++ni) {
#pragma unroll
      for (int qq = 0; qq < 4; ++qq) {
        T2t[(size_t)b * 1048576 + (size_t)(d0 + lg * 4 + qq) * 1024 +
            n * 64 + ni * 16 + lr] = f2bf(acc[hh][ni][qq]);
      }
    }
  }

  // q-tail: stream-convert this block's 64KB chunk of q -> Qb
  const float4* src = reinterpret_cast<const float4*>(qsrc) + (size_t)o * 4096;
  ushort4* dst = reinterpret_cast<ushort4*>(qdst) + (size_t)o * 4096;
#pragma unroll
  for (int rnd = 0; rnd < 4; ++rnd) {
    float4 r[4];
#pragma unroll
    for (int i = 0; i < 4; ++i) r[i] = src[rnd * 1024 + i * 256 + tid];
#pragma unroll
    for (int i = 0; i < 4; ++i) {
      ushort4 oo;
      oo.x = f2bf(r[i].x); oo.y = f2bf(r[i].y);
      oo.z = f2bf(r[i].z); oo.w = f2bf(r[i].w);
      dst[rnd * 1024 + i * 256 + tid] = oo;
    }
  }
}

// ---------------- gemm2 (unchanged, proven): out = 0.125 * Qb @ T2t^T + bias ----------------
template <int VM>
__device__ __forceinline__ void waitVm() {
  if constexpr (VM == 16) asm volatile("s_waitcnt vmcnt(16)" ::: "memory");
  else if constexpr (VM == 8) asm volatile("s_waitcnt vmcnt(8)" ::: "memory");
  else asm volatile("s_waitcnt vmcnt(0)" ::: "memory");
}

__global__ __launch_bounds__(256, 1) void gemm2(const u16* __restrict__ Abase,
                                                const u16* __restrict__ Bbase,
                                                float* __restrict__ CoutF,
                                                const float* __restrict__ bias) {
  __shared__ u16 AB[4][2][128 * 64];  // 128 KB
  const int tid = threadIdx.x;
  const int wid = tid >> 6;
  const int lane = tid & 63;
  const int batch = blockIdx.y;
  const int tm = blockIdx.x >> 3;
  const int tn = blockIdx.x & 7;

  const u16* A = Abase + (size_t)batch * 1048576;
  const u16* B = Bbase + (size_t)batch * 1048576;
  const int row0A = tm * 128, row0B = tn * 128;

  const int wr = wid >> 1;
  const int wc = wid & 1;
  const int laneRow = lane & 15;
  const int hi8 = (lane >> 4) * 8;
  const int swz = (lane & 7) * 8;

  f32x4 acc[4][4] = {};

  auto stage = [&](int tIdx) {
    const int kt = tIdx * 64;
    u16* lA = &AB[tIdx & 3][0][0];
    u16* lB = &AB[tIdx & 3][1][0];
#pragma unroll
    for (int i = 0; i < 4; ++i) {
      int p = i * 256 + tid;
      int r = p >> 3;
      int sc = ((p & 7) ^ (r & 7)) * 8;
      const u16* gA = A + (size_t)(row0A + r) * 1024 + kt + sc;
      const u16* gB = B + (size_t)(row0B + r) * 1024 + kt + sc;
      __builtin_amdgcn_global_load_lds((const AS1 void*)gA,
                                       (AS3 void*)(lA + i * 2048 + wid * 512), 16, 0, 0);
      __builtin_amdgcn_global_load_lds((const AS1 void*)gB,
                                       (AS3 void*)(lB + i * 2048 + wid * 512), 16, 0, 0);
    }
  };

  auto compute = [&](int tIdx) {
    const u16* At = &AB[tIdx & 3][0][0];
    const u16* Bt = &AB[tIdx & 3][1][0];
    bf16x8 af[2][4], bq[2][4];
#pragma unroll
    for (int kh = 0; kh < 2; ++kh) {
      int cs = (kh * 32 + hi8) ^ swz;
#pragma unroll
      for (int mi = 0; mi < 4; ++mi)
        af[kh][mi] = *reinterpret_cast<const bf16x8*>(
            &At[(wr * 64 + mi * 16 + laneRow) * 64 + cs]);
#pragma unroll
      for (int ni = 0; ni < 4; ++ni)
        bq[kh][ni] = *reinterpret_cast<const bf16x8*>(
            &Bt[(wc * 64 + ni * 16 + laneRow) * 64 + cs]);
    }
#pragma unroll
    for (int kh = 0; kh < 2; ++kh)
#pragma unroll
      for (int mi = 0; mi < 4; ++mi)
#pragma unroll
        for (int ni = 0; ni < 4; ++ni)
          acc[mi][ni] = __builtin_amdgcn_mfma_f32_16x16x32_bf16(
              af[kh][mi], bq[kh][ni], acc[mi][ni], 0, 0, 0);
  };

  stage(0); stage(1); stage(2);
  for (int t = 0; t < 13; ++t) {
    waitVm<16>();
    __builtin_amdgcn_s_barrier();
    stage(t + 3);
    compute(t);
  }
  waitVm<16>(); __builtin_amdgcn_s_barrier(); compute(13);
  waitVm<8>();  __builtin_amdgcn_s_barrier(); compute(14);
  waitVm<0>();  __builtin_amdgcn_s_barrier(); compute(15);

#pragma unroll
  for (int mi = 0; mi < 4; ++mi) {
#pragma unroll
    for (int ni = 0; ni < 4; ++ni) {
      int colg = tn * 128 + wc * 64 + ni * 16 + laneRow;
#pragma unroll
      for (int qq = 0; qq < 4; ++qq) {
        int rowg = tm * 128 + wr * 64 + mi * 16 + (lane >> 4) * 4 + qq;
        CoutF[(size_t)batch * 1048576 + (size_t)rowg * 1024 + colg] =
            acc[mi][ni][qq] * 0.125f + bias[colg];
      }
    }
  }
}

extern "C" void kernel_launch(void* const* d_in, const int* in_sizes, int n_in,
                              void* d_out, int out_size, void* d_ws, size_t ws_size,
                              hipStream_t stream) {
  const float* q    = (const float*)d_in[0];
  const float* k    = (const float*)d_in[1];
  // d_in[2] = v — unused by the reference output
  const float* fc_w = (const float*)d_in[3];
  const float* fc_b = (const float*)d_in[4];
  float* out = (float*)d_out;

  char* ws = (char*)d_ws;
  if (ws_size < 58720256) return;
  u16* Qb  = (u16*)(ws);             // [4][1024][1024]  8.4 MB
  u16* Kt  = (u16*)(ws + 8388608);   // [16][256][1024]  8.4 MB
  u16* T2t = (u16*)(ws + 50331648);  // [4][1024][1024]  8.4 MB

  prep_k<<<1024, 256, 0, stream>>>(k, Kt);
  gemm1f<<<256, 256, 0, stream>>>(fc_w, Kt, T2t, q, Qb);
  gemm2<<<dim3(64, 4), 256, 0, stream>>>(Qb, T2t, out, fc_b);
}